// Round 2
// baseline (287.037 us; speedup 1.0000x reference)
//
#include <hip/hip_runtime.h>
#include <hip/hip_bf16.h>
#include <cstdint>
#include <cstddef>

// Shapes (compile-time)
#define Bq 4
#define Nseq 1024
#define Dm 1024
#define Hh 16
#define HDd 64
#define FFd 2048
#define Mrows 4096  // B*N

typedef __attribute__((ext_vector_type(8))) short bf16x8;   // 8 bf16 = 4 VGPRs
typedef __attribute__((ext_vector_type(4))) float f32x4;

__device__ __forceinline__ void gl_lds16(const void* g, void* l) {
  // async global->LDS, 16B per lane; LDS dest = wave-uniform base + lane*16
  __builtin_amdgcn_global_load_lds(
      (const __attribute__((address_space(1))) unsigned int*)g,
      (__attribute__((address_space(3))) unsigned int*)l, 16, 0, 0);
}

__device__ __forceinline__ unsigned short f2b(float f) {
  union { __hip_bfloat16 h; unsigned short u; } cv;
  cv.h = __float2bfloat16(f);
  return cv.u;
}

// ---------------- transpose + cast: src f32 [K][Ncols] -> dst bf16 [Ncols][K]
__global__ __launch_bounds__(256) void transpose_cast_k(
    const float* __restrict__ src, __hip_bfloat16* __restrict__ dst,
    int K, int Ncols) {
  __shared__ float tile[32][33];
  const int n0 = blockIdx.x * 32, k0 = blockIdx.y * 32;
  const int tx = threadIdx.x & 31, ty = threadIdx.x >> 5;  // ty 0..7
#pragma unroll
  for (int i = 0; i < 32; i += 8)
    tile[ty + i][tx] = src[(size_t)(k0 + ty + i) * Ncols + n0 + tx];
  __syncthreads();
#pragma unroll
  for (int i = 0; i < 32; i += 8)
    dst[(size_t)(n0 + ty + i) * K + k0 + tx] = __float2bfloat16(tile[tx][ty + i]);
}

// ---------------- layernorm: f32 [4096][1024] row -> bf16 out
__global__ __launch_bounds__(256) void ln_kernel(
    const float* __restrict__ x, const float* __restrict__ gw,
    const float* __restrict__ bw, __hip_bfloat16* __restrict__ out) {
  const int row = blockIdx.x;
  const float4 v = reinterpret_cast<const float4*>(x + (size_t)row * Dm)[threadIdx.x];
  float s1 = v.x + v.y + v.z + v.w;
  float s2 = v.x * v.x + v.y * v.y + v.z * v.z + v.w * v.w;
#pragma unroll
  for (int m = 1; m < 64; m <<= 1) {
    s1 += __shfl_xor(s1, m);
    s2 += __shfl_xor(s2, m);
  }
  __shared__ float a1[4], a2[4];
  const int wv = threadIdx.x >> 6;
  if ((threadIdx.x & 63) == 0) { a1[wv] = s1; a2[wv] = s2; }
  __syncthreads();
  s1 = a1[0] + a1[1] + a1[2] + a1[3];
  s2 = a2[0] + a2[1] + a2[2] + a2[3];
  const float mu = s1 * (1.f / Dm);
  const float rs = rsqrtf(s2 * (1.f / Dm) - mu * mu + 1e-5f);
  const float4 g4 = reinterpret_cast<const float4*>(gw)[threadIdx.x];
  const float4 b4 = reinterpret_cast<const float4*>(bw)[threadIdx.x];
  ushort4 o;
  o.x = f2b((v.x - mu) * rs * g4.x + b4.x);
  o.y = f2b((v.y - mu) * rs * g4.y + b4.y);
  o.z = f2b((v.z - mu) * rs * g4.z + b4.z);
  o.w = f2b((v.w - mu) * rs * g4.w + b4.w);
  reinterpret_cast<ushort4*>(out + (size_t)row * Dm)[threadIdx.x] = o;
}

// ---------------- GEMM: C[M][Nd] = A[M][K] @ BT[Nd][K]^T + bias, fused epilogues
// EPI 0: scatter q(+scale)/k/v(transposed) bf16
// EPI 1: f32 out = acc + bias + res   (residual add)
// EPI 2: bf16 out = gelu(acc + bias)
template <int EPI>
__global__ __launch_bounds__(256, 2) void gemm_bt(
    const __hip_bfloat16* __restrict__ A, const __hip_bfloat16* __restrict__ BT,
    const float* __restrict__ bias, const float* __restrict__ res,
    float* __restrict__ outF, __hip_bfloat16* __restrict__ outB,
    __hip_bfloat16* __restrict__ qb, __hip_bfloat16* __restrict__ kb,
    __hip_bfloat16* __restrict__ vtb, int Ndim, int Kdim) {
  __shared__ alignas(16) __hip_bfloat16 As[128 * 32];
  __shared__ alignas(16) __hip_bfloat16 Bs[128 * 32];
  const int tid = threadIdx.x;
  const int wv = tid >> 6, ln = tid & 63;
  const int wr = wv >> 1, wc = wv & 1;
  const int rowBase = blockIdx.y * 128;
  const int colBase = blockIdx.x * 128;

  f32x4 acc[4][4];
#pragma unroll
  for (int i = 0; i < 4; ++i)
#pragma unroll
    for (int j = 0; j < 4; ++j) acc[i][j] = {0.f, 0.f, 0.f, 0.f};

  const int lr = ln >> 2;        // row within 16-row staging chunk
  const int lc = (ln & 3) * 8;   // k-element offset within row
  const int fr = ln & 15, kq = (ln >> 4) * 8;

  for (int k0 = 0; k0 < Kdim; k0 += 32) {
#pragma unroll
    for (int c = 0; c < 2; ++c) {
      const int chunk = c * 4 + wv;  // 0..7, 16 rows each
      gl_lds16(A + (size_t)(rowBase + chunk * 16 + lr) * Kdim + k0 + lc,
               (char*)As + chunk * 1024);
      gl_lds16(BT + (size_t)(colBase + chunk * 16 + lr) * Kdim + k0 + lc,
               (char*)Bs + chunk * 1024);
    }
    __syncthreads();
    bf16x8 af[4], bfr[4];
#pragma unroll
    for (int i = 0; i < 4; ++i)
      af[i] = *reinterpret_cast<const bf16x8*>(As + (wr * 64 + i * 16 + fr) * 32 + kq);
#pragma unroll
    for (int j = 0; j < 4; ++j)
      bfr[j] = *reinterpret_cast<const bf16x8*>(Bs + (wc * 64 + j * 16 + fr) * 32 + kq);
#pragma unroll
    for (int i = 0; i < 4; ++i)
#pragma unroll
      for (int j = 0; j < 4; ++j)
        acc[i][j] = __builtin_amdgcn_mfma_f32_16x16x32_bf16(af[i], bfr[j], acc[i][j], 0, 0, 0);
    __syncthreads();
  }

  // epilogue: lane holds D[row=(ln>>4)*4+ii][col=ln&15] per fragment
  const int rq = (ln >> 4) * 4;
#pragma unroll
  for (int i = 0; i < 4; ++i) {
#pragma unroll
    for (int j = 0; j < 4; ++j) {
      const int gc = colBase + wc * 64 + j * 16 + fr;
      const float bv = bias[gc];
#pragma unroll
      for (int ii = 0; ii < 4; ++ii) {
        const int gr = rowBase + wr * 64 + i * 16 + rq + ii;
        float v = acc[i][j][ii] + bv;
        if constexpr (EPI == 0) {
          const int which = gc >> 10;
          const int dcol = gc & 1023;
          const int h = dcol >> 6, hd = dcol & 63;
          const int b = gr >> 10, n = gr & 1023;
          const size_t bh = (size_t)(b * Hh + h);
          if (which == 0)
            qb[(bh * Nseq + n) * HDd + hd] = __float2bfloat16(v * 0.125f);
          else if (which == 1)
            kb[(bh * Nseq + n) * HDd + hd] = __float2bfloat16(v);
          else
            vtb[(bh * HDd + hd) * Nseq + n] = __float2bfloat16(v);
        } else if constexpr (EPI == 1) {
          outF[(size_t)gr * Ndim + gc] = v + res[(size_t)gr * Ndim + gc];
        } else {  // EPI == 2, exact GELU
          outB[(size_t)gr * Ndim + gc] =
              __float2bfloat16(0.5f * v * (1.f + erff(v * 0.70710678118f)));
        }
      }
    }
  }
}

// ---------------- flash attention v2: barrier-free, K/V fragments direct from
// global (L2-resident: 128KB K + 128KB V per (b,h), 16-block reuse). Only LDS
// use is the per-wave P transpose buffer (padded rows: 144B, bank-safe).
__global__ __launch_bounds__(256, 2) void attn_kernel(
    const __hip_bfloat16* __restrict__ q, const __hip_bfloat16* __restrict__ k,
    const __hip_bfloat16* __restrict__ vt, __hip_bfloat16* __restrict__ attn) {
  __shared__ alignas(16) __hip_bfloat16 Ps[4][16 * 72];  // per-wave, 72-elem rows
  const int tid = threadIdx.x, wv = tid >> 6, ln = tid & 63;
  const int bh = blockIdx.x >> 4, qt = blockIdx.x & 15;
  const int b = bh >> 4, h = bh & 15;
  const int fr = ln & 15, kq8 = (ln >> 4) * 8;

  // Q fragments straight from global (16 q-rows per wave)
  const __hip_bfloat16* qsrc = q + ((size_t)bh * Nseq + qt * 64 + wv * 16) * HDd;
  const bf16x8 aq0 = *reinterpret_cast<const bf16x8*>(qsrc + fr * 64 + kq8);
  const bf16x8 aq1 = *reinterpret_cast<const bf16x8*>(qsrc + fr * 64 + 32 + kq8);

  float mrun[4], lrun[4];
  f32x4 accO[4];
#pragma unroll
  for (int i = 0; i < 4; ++i) { mrun[i] = -1e30f; lrun[i] = 0.f; }
#pragma unroll
  for (int j = 0; j < 4; ++j) accO[j] = {0.f, 0.f, 0.f, 0.f};

  const __hip_bfloat16* kbase = k + (size_t)bh * Nseq * HDd;
  const __hip_bfloat16* vbase = vt + (size_t)bh * HDd * Nseq;
  __hip_bfloat16* pw = &Ps[wv][0];

  for (int kt = 0; kt < 16; ++kt) {
    // scores: 16q x 64kv per wave; K fragments direct from global
    const __hip_bfloat16* kt0 = kbase + (size_t)kt * 64 * HDd;
    f32x4 sa[4];
#pragma unroll
    for (int j = 0; j < 4; ++j) sa[j] = {0.f, 0.f, 0.f, 0.f};
#pragma unroll
    for (int j = 0; j < 4; ++j) {
      const bf16x8 bk0 = *reinterpret_cast<const bf16x8*>(kt0 + (j * 16 + fr) * 64 + kq8);
      const bf16x8 bk1 = *reinterpret_cast<const bf16x8*>(kt0 + (j * 16 + fr) * 64 + 32 + kq8);
      sa[j] = __builtin_amdgcn_mfma_f32_16x16x32_bf16(aq0, bk0, sa[j], 0, 0, 0);
      sa[j] = __builtin_amdgcn_mfma_f32_16x16x32_bf16(aq1, bk1, sa[j], 0, 0, 0);
    }

    // online softmax; row r = (ln>>4)*4+i, 16 lanes (fr) share a row
    float tmax[4];
#pragma unroll
    for (int i = 0; i < 4; ++i)
      tmax[i] = fmaxf(fmaxf(sa[0][i], sa[1][i]), fmaxf(sa[2][i], sa[3][i]));
#pragma unroll
    for (int m = 1; m < 16; m <<= 1)
#pragma unroll
      for (int i = 0; i < 4; ++i) tmax[i] = fmaxf(tmax[i], __shfl_xor(tmax[i], m));
    float sc[4], tsum[4];
#pragma unroll
    for (int i = 0; i < 4; ++i) {
      const float mn = fmaxf(mrun[i], tmax[i]);
      sc[i] = __expf(mrun[i] - mn);
      mrun[i] = mn;
      tsum[i] = 0.f;
    }
    float p[4][4];
#pragma unroll
    for (int j = 0; j < 4; ++j)
#pragma unroll
      for (int i = 0; i < 4; ++i) {
        const float e = __expf(sa[j][i] - mrun[i]);
        p[j][i] = e;
        tsum[i] += e;
      }
#pragma unroll
    for (int m = 1; m < 16; m <<= 1)
#pragma unroll
      for (int i = 0; i < 4; ++i) tsum[i] += __shfl_xor(tsum[i], m);
#pragma unroll
    for (int i = 0; i < 4; ++i) lrun[i] = lrun[i] * sc[i] + tsum[i];
#pragma unroll
    for (int j = 0; j < 4; ++j)
#pragma unroll
      for (int i = 0; i < 4; ++i) accO[j][i] *= sc[i];

    // P (D-layout) -> per-wave LDS -> A-layout; wave-private, no barrier
#pragma unroll
    for (int j = 0; j < 4; ++j)
#pragma unroll
      for (int i = 0; i < 4; ++i)
        pw[((ln >> 4) * 4 + i) * 72 + j * 16 + fr] = __float2bfloat16(p[j][i]);

    // PV: O[16q][64hd] += P @ V ; V^T fragments direct from global
#pragma unroll
    for (int s2 = 0; s2 < 2; ++s2) {
      const bf16x8 ap = *reinterpret_cast<const bf16x8*>(pw + fr * 72 + s2 * 32 + kq8);
#pragma unroll
      for (int j = 0; j < 4; ++j) {
        const bf16x8 bv = *reinterpret_cast<const bf16x8*>(
            vbase + (size_t)(j * 16 + fr) * Nseq + kt * 64 + s2 * 32 + kq8);
        accO[j] = __builtin_amdgcn_mfma_f32_16x16x32_bf16(ap, bv, accO[j], 0, 0, 0);
      }
    }
  }

  float inv[4];
#pragma unroll
  for (int i = 0; i < 4; ++i) inv[i] = 1.f / lrun[i];
#pragma unroll
  for (int j = 0; j < 4; ++j)
#pragma unroll
    for (int i = 0; i < 4; ++i)
      attn[((size_t)b * Nseq + qt * 64 + wv * 16 + (ln >> 4) * 4 + i) * Dm + h * 64 +
           j * 16 + fr] = __float2bfloat16(accO[j][i] * inv[i]);
}

extern "C" void kernel_launch(void* const* d_in, const int* in_sizes, int n_in,
                              void* d_out, int out_size, void* d_ws, size_t ws_size,
                              hipStream_t stream) {
  (void)in_sizes; (void)n_in; (void)out_size; (void)ws_size;
  const float* x     = (const float*)d_in[0];
  const float* ln1_g = (const float*)d_in[1];
  const float* ln1_b = (const float*)d_in[2];
  const float* qkv_w = (const float*)d_in[3];
  const float* qkv_b = (const float*)d_in[4];
  const float* out_w = (const float*)d_in[5];
  const float* out_b = (const float*)d_in[6];
  const float* ln2_g = (const float*)d_in[7];
  const float* ln2_b = (const float*)d_in[8];
  const float* w1    = (const float*)d_in[9];
  const float* b1    = (const float*)d_in[10];
  const float* w2    = (const float*)d_in[11];
  const float* b2    = (const float*)d_in[12];
  float* outp = (float*)d_out;

  char* ws = (char*)d_ws;
  size_t off = 0;
  auto take = [&](size_t bytes) {
    char* p = ws + off;
    off += (bytes + 255) & ~(size_t)255;
    return p;
  };
  __hip_bfloat16* wqkv_t = (__hip_bfloat16*)take((size_t)3 * Dm * Dm * 2);
  __hip_bfloat16* wout_t = (__hip_bfloat16*)take((size_t)Dm * Dm * 2);
  __hip_bfloat16* w1_t   = (__hip_bfloat16*)take((size_t)FFd * Dm * 2);
  __hip_bfloat16* w2_t   = (__hip_bfloat16*)take((size_t)Dm * FFd * 2);
  __hip_bfloat16* xn     = (__hip_bfloat16*)take((size_t)Mrows * Dm * 2);  // reused as LN2 out
  __hip_bfloat16* qb     = (__hip_bfloat16*)take((size_t)Mrows * Dm * 2);
  __hip_bfloat16* kb     = (__hip_bfloat16*)take((size_t)Mrows * Dm * 2);
  __hip_bfloat16* vtb    = (__hip_bfloat16*)take((size_t)Mrows * Dm * 2);
  __hip_bfloat16* attn   = (__hip_bfloat16*)take((size_t)Mrows * Dm * 2);
  float*          x1     = (float*)take((size_t)Mrows * Dm * 4);
  __hip_bfloat16* gbuf   = (__hip_bfloat16*)take((size_t)Mrows * FFd * 2);

  const dim3 blk(256);
  // weight transposes (f32 [K][N] -> bf16 [N][K])
  transpose_cast_k<<<dim3(3 * Dm / 32, Dm / 32), blk, 0, stream>>>(qkv_w, wqkv_t, Dm, 3 * Dm);
  transpose_cast_k<<<dim3(Dm / 32, Dm / 32), blk, 0, stream>>>(out_w, wout_t, Dm, Dm);
  transpose_cast_k<<<dim3(FFd / 32, Dm / 32), blk, 0, stream>>>(w1, w1_t, Dm, FFd);
  transpose_cast_k<<<dim3(Dm / 32, FFd / 32), blk, 0, stream>>>(w2, w2_t, FFd, Dm);
  // LN1
  ln_kernel<<<dim3(Mrows), blk, 0, stream>>>(x, ln1_g, ln1_b, xn);
  // QKV projection, scatter q/k/v^T
  gemm_bt<0><<<dim3(3 * Dm / 128, Mrows / 128), blk, 0, stream>>>(
      xn, wqkv_t, qkv_b, nullptr, nullptr, nullptr, qb, kb, vtb, 3 * Dm, Dm);
  // attention
  attn_kernel<<<dim3(Bq * Hh * (Nseq / 64)), blk, 0, stream>>>(qb, kb, vtb, attn);
  // output projection + residual -> x1 (f32)
  gemm_bt<1><<<dim3(Dm / 128, Mrows / 128), blk, 0, stream>>>(
      attn, wout_t, out_b, x, x1, nullptr, nullptr, nullptr, nullptr, Dm, Dm);
  // LN2
  ln_kernel<<<dim3(Mrows), blk, 0, stream>>>(x1, ln2_g, ln2_b, xn);
  // FFN1 + GELU -> gbuf (bf16)
  gemm_bt<2><<<dim3(FFd / 128, Mrows / 128), blk, 0, stream>>>(
      xn, w1_t, b1, nullptr, nullptr, gbuf, nullptr, nullptr, nullptr, FFd, Dm);
  // FFN2 + residual -> out (f32)
  gemm_bt<1><<<dim3(Dm / 128, Mrows / 128), blk, 0, stream>>>(
      gbuf, w2_t, b2, x1, outp, nullptr, nullptr, nullptr, nullptr, Dm, FFd);
}

// Round 3
// 235.256 us; speedup vs baseline: 1.2201x; 1.2201x over previous
//
#include <hip/hip_runtime.h>
#include <hip/hip_bf16.h>
#include <cstdint>
#include <cstddef>

// Shapes (compile-time)
#define Bq 4
#define Nseq 1024
#define Dm 1024
#define Hh 16
#define HDd 64
#define FFd 2048
#define Mrows 4096  // B*N

typedef __attribute__((ext_vector_type(8))) short bf16x8;   // 8 bf16 = 4 VGPRs
typedef __attribute__((ext_vector_type(4))) float f32x4;

__device__ __forceinline__ void gl_lds16(const void* g, void* l) {
  // async global->LDS, 16B per lane; LDS dest = wave-uniform base + lane*16
  __builtin_amdgcn_global_load_lds(
      (const __attribute__((address_space(1))) unsigned int*)g,
      (__attribute__((address_space(3))) unsigned int*)l, 16, 0, 0);
}

__device__ __forceinline__ unsigned short f2b(float f) {
  union { __hip_bfloat16 h; unsigned short u; } cv;
  cv.h = __float2bfloat16(f);
  return cv.u;
}

// ---------------- transpose + cast: src f32 [K][Ncols] -> dst bf16 [Ncols][K]
__global__ __launch_bounds__(256) void transpose_cast_k(
    const float* __restrict__ src, __hip_bfloat16* __restrict__ dst,
    int K, int Ncols) {
  __shared__ float tile[32][33];
  const int n0 = blockIdx.x * 32, k0 = blockIdx.y * 32;
  const int tx = threadIdx.x & 31, ty = threadIdx.x >> 5;  // ty 0..7
#pragma unroll
  for (int i = 0; i < 32; i += 8)
    tile[ty + i][tx] = src[(size_t)(k0 + ty + i) * Ncols + n0 + tx];
  __syncthreads();
#pragma unroll
  for (int i = 0; i < 32; i += 8)
    dst[(size_t)(n0 + ty + i) * K + k0 + tx] = __float2bfloat16(tile[tx][ty + i]);
}

// ---------------- layernorm: f32 [4096][1024] row -> bf16 out
__global__ __launch_bounds__(256) void ln_kernel(
    const float* __restrict__ x, const float* __restrict__ gw,
    const float* __restrict__ bw, __hip_bfloat16* __restrict__ out) {
  const int row = blockIdx.x;
  const float4 v = reinterpret_cast<const float4*>(x + (size_t)row * Dm)[threadIdx.x];
  float s1 = v.x + v.y + v.z + v.w;
  float s2 = v.x * v.x + v.y * v.y + v.z * v.z + v.w * v.w;
#pragma unroll
  for (int m = 1; m < 64; m <<= 1) {
    s1 += __shfl_xor(s1, m);
    s2 += __shfl_xor(s2, m);
  }
  __shared__ float a1[4], a2[4];
  const int wv = threadIdx.x >> 6;
  if ((threadIdx.x & 63) == 0) { a1[wv] = s1; a2[wv] = s2; }
  __syncthreads();
  s1 = a1[0] + a1[1] + a1[2] + a1[3];
  s2 = a2[0] + a2[1] + a2[2] + a2[3];
  const float mu = s1 * (1.f / Dm);
  const float rs = rsqrtf(s2 * (1.f / Dm) - mu * mu + 1e-5f);
  const float4 g4 = reinterpret_cast<const float4*>(gw)[threadIdx.x];
  const float4 b4 = reinterpret_cast<const float4*>(bw)[threadIdx.x];
  ushort4 o;
  o.x = f2b((v.x - mu) * rs * g4.x + b4.x);
  o.y = f2b((v.y - mu) * rs * g4.y + b4.y);
  o.z = f2b((v.z - mu) * rs * g4.z + b4.z);
  o.w = f2b((v.w - mu) * rs * g4.w + b4.w);
  reinterpret_cast<ushort4*>(out + (size_t)row * Dm)[threadIdx.x] = o;
}

// ---------------- GEMM: C[M][Nd] = A[M][K] @ BT[Nd][K]^T + bias, fused epilogues
// EPI 0: scatter q(+scale)/k/v(transposed) bf16
// EPI 1: f32 out = acc + bias + res   (residual add)
// EPI 2: bf16 out = gelu(acc + bias)
template <int EPI>
__global__ __launch_bounds__(256, 2) void gemm_bt(
    const __hip_bfloat16* __restrict__ A, const __hip_bfloat16* __restrict__ BT,
    const float* __restrict__ bias, const float* __restrict__ res,
    float* __restrict__ outF, __hip_bfloat16* __restrict__ outB,
    __hip_bfloat16* __restrict__ qb, __hip_bfloat16* __restrict__ kb,
    __hip_bfloat16* __restrict__ vtb, int Ndim, int Kdim) {
  __shared__ alignas(16) __hip_bfloat16 As[128 * 32];
  __shared__ alignas(16) __hip_bfloat16 Bs[128 * 32];
  const int tid = threadIdx.x;
  const int wv = tid >> 6, ln = tid & 63;
  const int wr = wv >> 1, wc = wv & 1;
  const int rowBase = blockIdx.y * 128;
  const int colBase = blockIdx.x * 128;

  f32x4 acc[4][4];
#pragma unroll
  for (int i = 0; i < 4; ++i)
#pragma unroll
    for (int j = 0; j < 4; ++j) acc[i][j] = {0.f, 0.f, 0.f, 0.f};

  const int lr = ln >> 2;        // row within 16-row staging chunk
  const int lc = (ln & 3) * 8;   // k-element offset within row
  const int fr = ln & 15, kq = (ln >> 4) * 8;

  for (int k0 = 0; k0 < Kdim; k0 += 32) {
#pragma unroll
    for (int c = 0; c < 2; ++c) {
      const int chunk = c * 4 + wv;  // 0..7, 16 rows each
      gl_lds16(A + (size_t)(rowBase + chunk * 16 + lr) * Kdim + k0 + lc,
               (char*)As + chunk * 1024);
      gl_lds16(BT + (size_t)(colBase + chunk * 16 + lr) * Kdim + k0 + lc,
               (char*)Bs + chunk * 1024);
    }
    __syncthreads();
    bf16x8 af[4], bfr[4];
#pragma unroll
    for (int i = 0; i < 4; ++i)
      af[i] = *reinterpret_cast<const bf16x8*>(As + (wr * 64 + i * 16 + fr) * 32 + kq);
#pragma unroll
    for (int j = 0; j < 4; ++j)
      bfr[j] = *reinterpret_cast<const bf16x8*>(Bs + (wc * 64 + j * 16 + fr) * 32 + kq);
#pragma unroll
    for (int i = 0; i < 4; ++i)
#pragma unroll
      for (int j = 0; j < 4; ++j)
        acc[i][j] = __builtin_amdgcn_mfma_f32_16x16x32_bf16(af[i], bfr[j], acc[i][j], 0, 0, 0);
    __syncthreads();
  }

  // epilogue: lane holds D[row=(ln>>4)*4+ii][col=ln&15] per fragment
  const int rq = (ln >> 4) * 4;
#pragma unroll
  for (int i = 0; i < 4; ++i) {
#pragma unroll
    for (int j = 0; j < 4; ++j) {
      const int gc = colBase + wc * 64 + j * 16 + fr;
      const float bv = bias[gc];
#pragma unroll
      for (int ii = 0; ii < 4; ++ii) {
        const int gr = rowBase + wr * 64 + i * 16 + rq + ii;
        float v = acc[i][j][ii] + bv;
        if constexpr (EPI == 0) {
          const int which = gc >> 10;
          const int dcol = gc & 1023;
          const int h = dcol >> 6, hd = dcol & 63;
          const int b = gr >> 10, n = gr & 1023;
          const size_t bh = (size_t)(b * Hh + h);
          if (which == 0)
            qb[(bh * Nseq + n) * HDd + hd] = __float2bfloat16(v * 0.125f);
          else if (which == 1)
            kb[(bh * Nseq + n) * HDd + hd] = __float2bfloat16(v);
          else
            vtb[(bh * HDd + hd) * Nseq + n] = __float2bfloat16(v);
        } else if constexpr (EPI == 1) {
          outF[(size_t)gr * Ndim + gc] = v + res[(size_t)gr * Ndim + gc];
        } else {  // EPI == 2, exact GELU
          outB[(size_t)gr * Ndim + gc] =
              __float2bfloat16(0.5f * v * (1.f + erff(v * 0.70710678118f)));
        }
      }
    }
  }
}

// ---------------- flash attention v3: LDS-staged K/V with XOR-swizzle applied
// via pre-swizzled GLOBAL source (global_load_lds dest must stay linear) +
// matching swizzled ds_read addresses; double-buffered, one barrier per tile.
__global__ __launch_bounds__(256, 2) void attn_kernel(
    const __hip_bfloat16* __restrict__ q, const __hip_bfloat16* __restrict__ k,
    const __hip_bfloat16* __restrict__ vt, __hip_bfloat16* __restrict__ attn) {
  __shared__ alignas(16) __hip_bfloat16 Ks[2][64 * 64];
  __shared__ alignas(16) __hip_bfloat16 Vs[2][64 * 64];  // [hd][kv]
  __shared__ alignas(16) __hip_bfloat16 Ps[4][16 * 72];  // per-wave, pad-72 rows
  const int tid = threadIdx.x, wv = tid >> 6, ln = tid & 63;
  const int bh = blockIdx.x >> 4, qt = blockIdx.x & 15;
  const int b = bh >> 4, h = bh & 15;
  const int fr = ln & 15, qq = ln >> 4, kq8 = qq * 8;

  const __hip_bfloat16* kbase = k + (size_t)bh * Nseq * HDd;
  const __hip_bfloat16* vbase = vt + (size_t)bh * HDd * Nseq;

  // ---- staging geometry: tile row = 128B = 8 x 16B chunks; chunk of 8 rows/KB.
  // lane l covers (row st_r, col16 l&7); source col16 is XOR-swizzled by row&7.
  const int st_r = ln >> 3;            // 0..7 row within 8-row chunk
  const int st_c = (ln & 7) ^ st_r;    // swizzled 16B-chunk index within row

  // Q fragments straight from global (16 q-rows per wave; read once)
  const __hip_bfloat16* qsrc = q + ((size_t)bh * Nseq + qt * 64 + wv * 16) * HDd;
  const bf16x8 aq0 = *reinterpret_cast<const bf16x8*>(qsrc + fr * 64 + kq8);
  const bf16x8 aq1 = *reinterpret_cast<const bf16x8*>(qsrc + fr * 64 + 32 + kq8);

  float mrun[4], lrun[4];
  f32x4 accO[4];
#pragma unroll
  for (int i = 0; i < 4; ++i) { mrun[i] = -1e30f; lrun[i] = 0.f; }
#pragma unroll
  for (int j = 0; j < 4; ++j) accO[j] = {0.f, 0.f, 0.f, 0.f};

  // swizzled read offsets (bytes within a row) for the two 32-elem halves
  const int frb = fr * 128;
  const int cs0 = ((0 + qq) ^ (fr & 7)) * 16;
  const int cs1 = ((4 + qq) ^ (fr & 7)) * 16;
  __hip_bfloat16* pw = &Ps[wv][0];

  auto stage = [&](int buf, int kt) {
#pragma unroll
    for (int c = 0; c < 2; ++c) {
      const int chunk = wv * 2 + c;  // 0..7
      gl_lds16(kbase + ((size_t)kt * 64 + chunk * 8 + st_r) * HDd + st_c * 8,
               (char*)&Ks[buf][0] + chunk * 1024);
      gl_lds16(vbase + (size_t)(chunk * 8 + st_r) * Nseq + kt * 64 + st_c * 8,
               (char*)&Vs[buf][0] + chunk * 1024);
    }
  };

  stage(0, 0);
  __syncthreads();
  int cur = 0;

  for (int kt = 0; kt < 16; ++kt) {
    if (kt < 15) stage(cur ^ 1, kt + 1);  // prefetch next tile under compute

    const char* Kp = (const char*)&Ks[cur][0];
    const char* Vp = (const char*)&Vs[cur][0];

    // scores: 16q x 64kv per wave
    f32x4 sa[4];
#pragma unroll
    for (int j = 0; j < 4; ++j) sa[j] = {0.f, 0.f, 0.f, 0.f};
#pragma unroll
    for (int j = 0; j < 4; ++j) {
      const bf16x8 bk0 = *reinterpret_cast<const bf16x8*>(Kp + j * 2048 + frb + cs0);
      const bf16x8 bk1 = *reinterpret_cast<const bf16x8*>(Kp + j * 2048 + frb + cs1);
      sa[j] = __builtin_amdgcn_mfma_f32_16x16x32_bf16(aq0, bk0, sa[j], 0, 0, 0);
      sa[j] = __builtin_amdgcn_mfma_f32_16x16x32_bf16(aq1, bk1, sa[j], 0, 0, 0);
    }

    // online softmax; row r = qq*4+i, 16 lanes (fr) share a row
    float tmax[4];
#pragma unroll
    for (int i = 0; i < 4; ++i)
      tmax[i] = fmaxf(fmaxf(sa[0][i], sa[1][i]), fmaxf(sa[2][i], sa[3][i]));
#pragma unroll
    for (int m = 1; m < 16; m <<= 1)
#pragma unroll
      for (int i = 0; i < 4; ++i) tmax[i] = fmaxf(tmax[i], __shfl_xor(tmax[i], m));
    float sc[4], tsum[4];
#pragma unroll
    for (int i = 0; i < 4; ++i) {
      const float mn = fmaxf(mrun[i], tmax[i]);
      sc[i] = __expf(mrun[i] - mn);
      mrun[i] = mn;
      tsum[i] = 0.f;
    }
    float p[4][4];
#pragma unroll
    for (int j = 0; j < 4; ++j)
#pragma unroll
      for (int i = 0; i < 4; ++i) {
        const float e = __expf(sa[j][i] - mrun[i]);
        p[j][i] = e;
        tsum[i] += e;
      }
#pragma unroll
    for (int m = 1; m < 16; m <<= 1)
#pragma unroll
      for (int i = 0; i < 4; ++i) tsum[i] += __shfl_xor(tsum[i], m);
#pragma unroll
    for (int i = 0; i < 4; ++i) lrun[i] = lrun[i] * sc[i] + tsum[i];
#pragma unroll
    for (int j = 0; j < 4; ++j)
#pragma unroll
      for (int i = 0; i < 4; ++i) accO[j][i] *= sc[i];

    // P (D-layout) -> per-wave LDS -> A-layout; wave-private, no barrier
#pragma unroll
    for (int j = 0; j < 4; ++j)
#pragma unroll
      for (int i = 0; i < 4; ++i)
        pw[(qq * 4 + i) * 72 + j * 16 + fr] = __float2bfloat16(p[j][i]);

    // PV: O[16q][64hd] += P @ V
#pragma unroll
    for (int s2 = 0; s2 < 2; ++s2) {
      const bf16x8 ap = *reinterpret_cast<const bf16x8*>(pw + fr * 72 + s2 * 32 + kq8);
      const int csv = (s2 ? cs1 : cs0);
#pragma unroll
      for (int j = 0; j < 4; ++j) {
        const bf16x8 bv = *reinterpret_cast<const bf16x8*>(Vp + j * 2048 + frb + csv);
        accO[j] = __builtin_amdgcn_mfma_f32_16x16x32_bf16(ap, bv, accO[j], 0, 0, 0);
      }
    }

    __syncthreads();  // drains prefetch (vmcnt) + protects cur buffer reuse
    cur ^= 1;
  }

  float inv[4];
#pragma unroll
  for (int i = 0; i < 4; ++i) inv[i] = 1.f / lrun[i];
#pragma unroll
  for (int j = 0; j < 4; ++j)
#pragma unroll
    for (int i = 0; i < 4; ++i)
      attn[((size_t)b * Nseq + qt * 64 + wv * 16 + qq * 4 + i) * Dm + h * 64 +
           j * 16 + fr] = __float2bfloat16(accO[j][i] * inv[i]);
}

extern "C" void kernel_launch(void* const* d_in, const int* in_sizes, int n_in,
                              void* d_out, int out_size, void* d_ws, size_t ws_size,
                              hipStream_t stream) {
  (void)in_sizes; (void)n_in; (void)out_size; (void)ws_size;
  const float* x     = (const float*)d_in[0];
  const float* ln1_g = (const float*)d_in[1];
  const float* ln1_b = (const float*)d_in[2];
  const float* qkv_w = (const float*)d_in[3];
  const float* qkv_b = (const float*)d_in[4];
  const float* out_w = (const float*)d_in[5];
  const float* out_b = (const float*)d_in[6];
  const float* ln2_g = (const float*)d_in[7];
  const float* ln2_b = (const float*)d_in[8];
  const float* w1    = (const float*)d_in[9];
  const float* b1    = (const float*)d_in[10];
  const float* w2    = (const float*)d_in[11];
  const float* b2    = (const float*)d_in[12];
  float* outp = (float*)d_out;

  char* ws = (char*)d_ws;
  size_t off = 0;
  auto take = [&](size_t bytes) {
    char* p = ws + off;
    off += (bytes + 255) & ~(size_t)255;
    return p;
  };
  __hip_bfloat16* wqkv_t = (__hip_bfloat16*)take((size_t)3 * Dm * Dm * 2);
  __hip_bfloat16* wout_t = (__hip_bfloat16*)take((size_t)Dm * Dm * 2);
  __hip_bfloat16* w1_t   = (__hip_bfloat16*)take((size_t)FFd * Dm * 2);
  __hip_bfloat16* w2_t   = (__hip_bfloat16*)take((size_t)Dm * FFd * 2);
  __hip_bfloat16* xn     = (__hip_bfloat16*)take((size_t)Mrows * Dm * 2);  // reused as LN2 out
  __hip_bfloat16* qb     = (__hip_bfloat16*)take((size_t)Mrows * Dm * 2);
  __hip_bfloat16* kb     = (__hip_bfloat16*)take((size_t)Mrows * Dm * 2);
  __hip_bfloat16* vtb    = (__hip_bfloat16*)take((size_t)Mrows * Dm * 2);
  __hip_bfloat16* attn   = (__hip_bfloat16*)take((size_t)Mrows * Dm * 2);
  float*          x1     = (float*)take((size_t)Mrows * Dm * 4);
  __hip_bfloat16* gbuf   = (__hip_bfloat16*)take((size_t)Mrows * FFd * 2);

  const dim3 blk(256);
  // weight transposes (f32 [K][N] -> bf16 [N][K])
  transpose_cast_k<<<dim3(3 * Dm / 32, Dm / 32), blk, 0, stream>>>(qkv_w, wqkv_t, Dm, 3 * Dm);
  transpose_cast_k<<<dim3(Dm / 32, Dm / 32), blk, 0, stream>>>(out_w, wout_t, Dm, Dm);
  transpose_cast_k<<<dim3(FFd / 32, Dm / 32), blk, 0, stream>>>(w1, w1_t, Dm, FFd);
  transpose_cast_k<<<dim3(Dm / 32, FFd / 32), blk, 0, stream>>>(w2, w2_t, FFd, Dm);
  // LN1
  ln_kernel<<<dim3(Mrows), blk, 0, stream>>>(x, ln1_g, ln1_b, xn);
  // QKV projection, scatter q/k/v^T
  gemm_bt<0><<<dim3(3 * Dm / 128, Mrows / 128), blk, 0, stream>>>(
      xn, wqkv_t, qkv_b, nullptr, nullptr, nullptr, qb, kb, vtb, 3 * Dm, Dm);
  // attention
  attn_kernel<<<dim3(Bq * Hh * (Nseq / 64)), blk, 0, stream>>>(qb, kb, vtb, attn);
  // output projection + residual -> x1 (f32)
  gemm_bt<1><<<dim3(Dm / 128, Mrows / 128), blk, 0, stream>>>(
      attn, wout_t, out_b, x, x1, nullptr, nullptr, nullptr, nullptr, Dm, Dm);
  // LN2
  ln_kernel<<<dim3(Mrows), blk, 0, stream>>>(x1, ln2_g, ln2_b, xn);
  // FFN1 + GELU -> gbuf (bf16)
  gemm_bt<2><<<dim3(FFd / 128, Mrows / 128), blk, 0, stream>>>(
      xn, w1_t, b1, nullptr, nullptr, gbuf, nullptr, nullptr, nullptr, FFd, Dm);
  // FFN2 + residual -> out (f32)
  gemm_bt<1><<<dim3(Dm / 128, Mrows / 128), blk, 0, stream>>>(
      gbuf, w2_t, b2, x1, outp, nullptr, nullptr, nullptr, nullptr, Dm, FFd);
}

// Round 4
// 202.405 us; speedup vs baseline: 1.4181x; 1.1623x over previous
//
#include <hip/hip_runtime.h>
#include <hip/hip_bf16.h>
#include <cstdint>
#include <cstddef>

// Shapes (compile-time)
#define Bq 4
#define Nseq 1024
#define Dm 1024
#define Hh 16
#define HDd 64
#define FFd 2048
#define Mrows 4096  // B*N

typedef __attribute__((ext_vector_type(8))) short bf16x8;   // 8 bf16 = 4 VGPRs
typedef __attribute__((ext_vector_type(4))) float f32x4;
typedef __attribute__((ext_vector_type(16))) float f32x16;

__device__ __forceinline__ void gl_lds16(const void* g, void* l) {
  // async global->LDS, 16B per lane; LDS dest = wave-uniform base + lane*16
  __builtin_amdgcn_global_load_lds(
      (const __attribute__((address_space(1))) unsigned int*)g,
      (__attribute__((address_space(3))) unsigned int*)l, 16, 0, 0);
}

__device__ __forceinline__ unsigned short f2b(float f) {
  union { __hip_bfloat16 h; unsigned short u; } cv;
  cv.h = __float2bfloat16(f);
  return cv.u;
}

__device__ __forceinline__ unsigned cvt_pk_bf16(float a, float b) {
  unsigned r;
  asm("v_cvt_pk_bf16_f32 %0, %1, %2" : "=v"(r) : "v"(a), "v"(b));
  return r;  // low16 = bf16(a), high16 = bf16(b)
}

__device__ __forceinline__ void pl32_swap(unsigned& a, unsigned& b) {
  // a' = {a.lanes<32, b.lanes<32 (viewed from upper)}; b' = {a.hi, b.hi}
  asm("v_permlane32_swap_b32 %0, %1" : "+v"(a), "+v"(b));
}

// ---------------- transpose + cast: src f32 [K][Ncols] -> dst bf16 [Ncols][K]
__global__ __launch_bounds__(256) void transpose_cast_k(
    const float* __restrict__ src, __hip_bfloat16* __restrict__ dst,
    int K, int Ncols) {
  __shared__ float tile[32][33];
  const int n0 = blockIdx.x * 32, k0 = blockIdx.y * 32;
  const int tx = threadIdx.x & 31, ty = threadIdx.x >> 5;  // ty 0..7
#pragma unroll
  for (int i = 0; i < 32; i += 8)
    tile[ty + i][tx] = src[(size_t)(k0 + ty + i) * Ncols + n0 + tx];
  __syncthreads();
#pragma unroll
  for (int i = 0; i < 32; i += 8)
    dst[(size_t)(n0 + ty + i) * K + k0 + tx] = __float2bfloat16(tile[tx][ty + i]);
}

// ---------------- layernorm: f32 [4096][1024] row -> bf16 out
__global__ __launch_bounds__(256) void ln_kernel(
    const float* __restrict__ x, const float* __restrict__ gw,
    const float* __restrict__ bw, __hip_bfloat16* __restrict__ out) {
  const int row = blockIdx.x;
  const float4 v = reinterpret_cast<const float4*>(x + (size_t)row * Dm)[threadIdx.x];
  float s1 = v.x + v.y + v.z + v.w;
  float s2 = v.x * v.x + v.y * v.y + v.z * v.z + v.w * v.w;
#pragma unroll
  for (int m = 1; m < 64; m <<= 1) {
    s1 += __shfl_xor(s1, m);
    s2 += __shfl_xor(s2, m);
  }
  __shared__ float a1[4], a2[4];
  const int wv = threadIdx.x >> 6;
  if ((threadIdx.x & 63) == 0) { a1[wv] = s1; a2[wv] = s2; }
  __syncthreads();
  s1 = a1[0] + a1[1] + a1[2] + a1[3];
  s2 = a2[0] + a2[1] + a2[2] + a2[3];
  const float mu = s1 * (1.f / Dm);
  const float rs = rsqrtf(s2 * (1.f / Dm) - mu * mu + 1e-5f);
  const float4 g4 = reinterpret_cast<const float4*>(gw)[threadIdx.x];
  const float4 b4 = reinterpret_cast<const float4*>(bw)[threadIdx.x];
  ushort4 o;
  o.x = f2b((v.x - mu) * rs * g4.x + b4.x);
  o.y = f2b((v.y - mu) * rs * g4.y + b4.y);
  o.z = f2b((v.z - mu) * rs * g4.z + b4.z);
  o.w = f2b((v.w - mu) * rs * g4.w + b4.w);
  reinterpret_cast<ushort4*>(out + (size_t)row * Dm)[threadIdx.x] = o;
}

// ---------------- GEMM: C[M][Nd] = A[M][K] @ BT[Nd][K]^T + bias, fused epilogues
// EPI 0: scatter q(+scale)/k/v(transposed) bf16
// EPI 1: f32 out = acc + bias + res   (residual add)
// EPI 2: bf16 out = gelu(acc + bias)
template <int EPI>
__global__ __launch_bounds__(256, 2) void gemm_bt(
    const __hip_bfloat16* __restrict__ A, const __hip_bfloat16* __restrict__ BT,
    const float* __restrict__ bias, const float* __restrict__ res,
    float* __restrict__ outF, __hip_bfloat16* __restrict__ outB,
    __hip_bfloat16* __restrict__ qb, __hip_bfloat16* __restrict__ kb,
    __hip_bfloat16* __restrict__ vtb, int Ndim, int Kdim) {
  __shared__ alignas(16) __hip_bfloat16 As[128 * 32];
  __shared__ alignas(16) __hip_bfloat16 Bs[128 * 32];
  const int tid = threadIdx.x;
  const int wv = tid >> 6, ln = tid & 63;
  const int wr = wv >> 1, wc = wv & 1;
  const int rowBase = blockIdx.y * 128;
  const int colBase = blockIdx.x * 128;

  f32x4 acc[4][4];
#pragma unroll
  for (int i = 0; i < 4; ++i)
#pragma unroll
    for (int j = 0; j < 4; ++j) acc[i][j] = {0.f, 0.f, 0.f, 0.f};

  const int lr = ln >> 2;        // row within 16-row staging chunk
  const int lc = (ln & 3) * 8;   // k-element offset within row
  const int fr = ln & 15, kq = (ln >> 4) * 8;

  for (int k0 = 0; k0 < Kdim; k0 += 32) {
#pragma unroll
    for (int c = 0; c < 2; ++c) {
      const int chunk = c * 4 + wv;  // 0..7, 16 rows each
      gl_lds16(A + (size_t)(rowBase + chunk * 16 + lr) * Kdim + k0 + lc,
               (char*)As + chunk * 1024);
      gl_lds16(BT + (size_t)(colBase + chunk * 16 + lr) * Kdim + k0 + lc,
               (char*)Bs + chunk * 1024);
    }
    __syncthreads();
    bf16x8 af[4], bfr[4];
#pragma unroll
    for (int i = 0; i < 4; ++i)
      af[i] = *reinterpret_cast<const bf16x8*>(As + (wr * 64 + i * 16 + fr) * 32 + kq);
#pragma unroll
    for (int j = 0; j < 4; ++j)
      bfr[j] = *reinterpret_cast<const bf16x8*>(Bs + (wc * 64 + j * 16 + fr) * 32 + kq);
#pragma unroll
    for (int i = 0; i < 4; ++i)
#pragma unroll
      for (int j = 0; j < 4; ++j)
        acc[i][j] = __builtin_amdgcn_mfma_f32_16x16x32_bf16(af[i], bfr[j], acc[i][j], 0, 0, 0);
    __syncthreads();
  }

  // epilogue: lane holds D[row=(ln>>4)*4+ii][col=ln&15] per fragment
  const int rq = (ln >> 4) * 4;
#pragma unroll
  for (int i = 0; i < 4; ++i) {
#pragma unroll
    for (int j = 0; j < 4; ++j) {
      const int gc = colBase + wc * 64 + j * 16 + fr;
      const float bv = bias[gc];
#pragma unroll
      for (int ii = 0; ii < 4; ++ii) {
        const int gr = rowBase + wr * 64 + i * 16 + rq + ii;
        float v = acc[i][j][ii] + bv;
        if constexpr (EPI == 0) {
          const int which = gc >> 10;
          const int dcol = gc & 1023;
          const int h = dcol >> 6, hd = dcol & 63;
          const int b = gr >> 10, n = gr & 1023;
          const size_t bh = (size_t)(b * Hh + h);
          if (which == 0)
            qb[(bh * Nseq + n) * HDd + hd] = __float2bfloat16(v * 0.125f);
          else if (which == 1)
            kb[(bh * Nseq + n) * HDd + hd] = __float2bfloat16(v);
          else
            vtb[(bh * HDd + hd) * Nseq + n] = __float2bfloat16(v);
        } else if constexpr (EPI == 1) {
          outF[(size_t)gr * Ndim + gc] = v + res[(size_t)gr * Ndim + gc];
        } else {  // EPI == 2, exact GELU
          outB[(size_t)gr * Ndim + gc] =
              __float2bfloat16(0.5f * v * (1.f + erff(v * 0.70710678118f)));
        }
      }
    }
  }
}

// ---------------- flash attention v4: swapped-operand 32x32x16 MFMA.
// S^T = K·Q^T so each lane owns 32 scores of ONE q-row (q = lane&31) ->
// in-register softmax + 1 shfl_xor(32) per reduce. P^T -> PV B-fragments via
// v_cvt_pk_bf16_f32 + v_permlane32_swap (no LDS for P). PV swapped too:
// O^T = V^T·P^T keeps O lane-local per q-row. K/V^T staged in LDS with
// source-side XOR swizzle, double-buffered, one barrier/iter.
// Block = 4 waves x 32 q = 128 q-rows of one (b,h). Grid = 64*8 = 512.
__global__ __launch_bounds__(256, 2) void attn_kernel(
    const __hip_bfloat16* __restrict__ q, const __hip_bfloat16* __restrict__ k,
    const __hip_bfloat16* __restrict__ vt, __hip_bfloat16* __restrict__ attn) {
  __shared__ alignas(16) __hip_bfloat16 Ks[2][64 * 64];  // [kv][d]
  __shared__ alignas(16) __hip_bfloat16 Vs[2][64 * 64];  // [d][kv]
  const int tid = threadIdx.x, wv = tid >> 6, ln = tid & 63;
  const int bh = blockIdx.x >> 3, qt = blockIdx.x & 7;
  const int b = bh >> 4, h = bh & 15;
  const int lq = ln & 31;   // this lane's q-row (within wave) & matrix row idx
  const int hl = ln >> 5;   // half-wave: selects k-group of A/B fragments

  const __hip_bfloat16* kbase = k + (size_t)bh * Nseq * HDd;
  const __hip_bfloat16* vbase = vt + (size_t)bh * HDd * Nseq;

  // staging geometry: tile row = 128B = 8 x 16B chunks; lane covers
  // (row st_r, chunk l&7); source chunk XOR-swizzled by row&7.
  const int st_r = ln >> 3;
  const int st_c = (ln & 7) ^ st_r;

  // Q fragments (B-operand of S^T): lane holds Q[q=lq][d = s*16 + hl*8 + j]
  const __hip_bfloat16* qsrc = q + ((size_t)bh * Nseq + qt * 128 + wv * 32 + lq) * HDd;
  bf16x8 qf[4];
#pragma unroll
  for (int s = 0; s < 4; ++s)
    qf[s] = *reinterpret_cast<const bf16x8*>(qsrc + s * 16 + hl * 8);

  float mrun = -1e30f, lrun = 0.f;
  f32x16 ot0 = {}, ot1 = {};  // O^T accum: d = dt*32 + (r&3)+8*(r>>2)+4*hl, q = lq

  auto stage = [&](int buf, int kt) {
#pragma unroll
    for (int c = 0; c < 2; ++c) {
      const int chunk = wv * 2 + c;  // 0..7 (8 rows each)
      gl_lds16(kbase + ((size_t)kt * 64 + chunk * 8 + st_r) * HDd + st_c * 8,
               (char*)&Ks[buf][0] + chunk * 1024);
      gl_lds16(vbase + (size_t)(chunk * 8 + st_r) * Nseq + kt * 64 + st_c * 8,
               (char*)&Vs[buf][0] + chunk * 1024);
    }
  };

  stage(0, 0);
  __syncthreads();
  int cur = 0;

  for (int kt = 0; kt < 16; ++kt) {
    if (kt < 15) stage(cur ^ 1, kt + 1);  // prefetch next tile under compute

    const char* Kp = (const char*)&Ks[cur][0];
    const char* Vp = (const char*)&Vs[cur][0];

    // ---- S^T[kv][q] = K·Q^T : A = K-tile rows (kv = t*32 + lq)
    f32x16 st0 = {}, st1 = {};
#pragma unroll
    for (int t = 0; t < 2; ++t) {
      const int row = t * 32 + lq;
#pragma unroll
      for (int s = 0; s < 4; ++s) {
        const bf16x8 kf = *reinterpret_cast<const bf16x8*>(
            Kp + row * 128 + (((s * 2 + hl) ^ (row & 7)) * 16));
        if (t == 0) st0 = __builtin_amdgcn_mfma_f32_32x32x16_bf16(kf, qf[s], st0, 0, 0, 0);
        else        st1 = __builtin_amdgcn_mfma_f32_32x32x16_bf16(kf, qf[s], st1, 0, 0, 0);
      }
    }

    // ---- online softmax, fully in-register (lane owns q-row lq)
    float tmax = st0[0];
#pragma unroll
    for (int r = 1; r < 16; ++r) tmax = fmaxf(tmax, st0[r]);
#pragma unroll
    for (int r = 0; r < 16; ++r) tmax = fmaxf(tmax, st1[r]);
    tmax = fmaxf(tmax, __shfl_xor(tmax, 32));
    const float mn = fmaxf(mrun, tmax);
    const float sc = __expf(mrun - mn);
    mrun = mn;
    float tsum = 0.f;
#pragma unroll
    for (int r = 0; r < 16; ++r) {
      st0[r] = __expf(st0[r] - mn);
      tsum += st0[r];
    }
#pragma unroll
    for (int r = 0; r < 16; ++r) {
      st1[r] = __expf(st1[r] - mn);
      tsum += st1[r];
    }
    tsum += __shfl_xor(tsum, 32);
    lrun = lrun * sc + tsum;
#pragma unroll
    for (int r = 0; r < 16; ++r) { ot0[r] *= sc; ot1[r] *= sc; }

    // ---- P^T -> PV B-fragments via cvt_pk + permlane32_swap (T12)
    // group (t,g) = kv 16*(2t+g) .. +15 ; frag words [w0', w1', w2'', w3'']
    union PF { unsigned u[4]; bf16x8 v; } pf[4];
#pragma unroll
    for (int t = 0; t < 2; ++t)
#pragma unroll
      for (int g = 0; g < 2; ++g) {
        unsigned w0, w1, w2, w3;
        if (t == 0) {
          w0 = cvt_pk_bf16(st0[g * 8 + 0], st0[g * 8 + 1]);
          w1 = cvt_pk_bf16(st0[g * 8 + 2], st0[g * 8 + 3]);
          w2 = cvt_pk_bf16(st0[g * 8 + 4], st0[g * 8 + 5]);
          w3 = cvt_pk_bf16(st0[g * 8 + 6], st0[g * 8 + 7]);
        } else {
          w0 = cvt_pk_bf16(st1[g * 8 + 0], st1[g * 8 + 1]);
          w1 = cvt_pk_bf16(st1[g * 8 + 2], st1[g * 8 + 3]);
          w2 = cvt_pk_bf16(st1[g * 8 + 4], st1[g * 8 + 5]);
          w3 = cvt_pk_bf16(st1[g * 8 + 6], st1[g * 8 + 7]);
        }
        pl32_swap(w0, w2);  // w0 -> word0, w2 -> word2
        pl32_swap(w1, w3);  // w1 -> word1, w3 -> word3
        PF f;
        f.u[0] = w0; f.u[1] = w1; f.u[2] = w2; f.u[3] = w3;
        pf[t * 2 + g] = f;
      }

    // ---- O^T += V^T·P^T : A = V^T rows (d = dt*32 + lq), k = kv
#pragma unroll
    for (int dt = 0; dt < 2; ++dt) {
      const int row = dt * 32 + lq;
#pragma unroll
      for (int ks = 0; ks < 4; ++ks) {
        const bf16x8 vf = *reinterpret_cast<const bf16x8*>(
            Vp + row * 128 + (((ks * 2 + hl) ^ (row & 7)) * 16));
        if (dt == 0) ot0 = __builtin_amdgcn_mfma_f32_32x32x16_bf16(vf, pf[ks].v, ot0, 0, 0, 0);
        else         ot1 = __builtin_amdgcn_mfma_f32_32x32x16_bf16(vf, pf[ks].v, ot1, 0, 0, 0);
      }
    }

    __syncthreads();  // drains prefetch + protects buffer swap
    cur ^= 1;
  }

  // ---- epilogue: O^T/lrun -> LDS (freed Ks, wave-private 4KB) -> coalesced out
  const float inv = 1.f / lrun;
  char* swb = (char*)(&Ks[0][0] + wv * 2048);  // [32 q][64 d] bf16, swizzled
#pragma unroll
  for (int dt = 0; dt < 2; ++dt)
#pragma unroll
    for (int i = 0; i < 8; ++i) {
      const unsigned w = (dt == 0)
          ? cvt_pk_bf16(ot0[2 * i] * inv, ot0[2 * i + 1] * inv)
          : cvt_pk_bf16(ot1[2 * i] * inv, ot1[2 * i + 1] * inv);
      const int d0 = (2 * i & 2) + 8 * (i >> 1) + 4 * hl + 32 * dt;
      *(unsigned*)(swb + lq * 128 + (((d0 >> 3) ^ (lq & 7)) * 16) + (d0 & 7) * 2) = w;
    }
  // wave-private region: compiler orders ds_write->ds_read via lgkmcnt
  const int brow = b * Nseq + qt * 128 + wv * 32;
#pragma unroll
  for (int it = 0; it < 4; ++it) {
    const int qr = it * 8 + (ln >> 3);
    const bf16x8 o = *reinterpret_cast<const bf16x8*>(
        swb + qr * 128 + (((ln & 7) ^ (qr & 7)) * 16));
    *reinterpret_cast<bf16x8*>(attn + (size_t)(brow + qr) * Dm + h * 64 + (ln & 7) * 8) = o;
  }
}

extern "C" void kernel_launch(void* const* d_in, const int* in_sizes, int n_in,
                              void* d_out, int out_size, void* d_ws, size_t ws_size,
                              hipStream_t stream) {
  (void)in_sizes; (void)n_in; (void)out_size; (void)ws_size;
  const float* x     = (const float*)d_in[0];
  const float* ln1_g = (const float*)d_in[1];
  const float* ln1_b = (const float*)d_in[2];
  const float* qkv_w = (const float*)d_in[3];
  const float* qkv_b = (const float*)d_in[4];
  const float* out_w = (const float*)d_in[5];
  const float* out_b = (const float*)d_in[6];
  const float* ln2_g = (const float*)d_in[7];
  const float* ln2_b = (const float*)d_in[8];
  const float* w1    = (const float*)d_in[9];
  const float* b1    = (const float*)d_in[10];
  const float* w2    = (const float*)d_in[11];
  const float* b2    = (const float*)d_in[12];
  float* outp = (float*)d_out;

  char* ws = (char*)d_ws;
  size_t off = 0;
  auto take = [&](size_t bytes) {
    char* p = ws + off;
    off += (bytes + 255) & ~(size_t)255;
    return p;
  };
  __hip_bfloat16* wqkv_t = (__hip_bfloat16*)take((size_t)3 * Dm * Dm * 2);
  __hip_bfloat16* wout_t = (__hip_bfloat16*)take((size_t)Dm * Dm * 2);
  __hip_bfloat16* w1_t   = (__hip_bfloat16*)take((size_t)FFd * Dm * 2);
  __hip_bfloat16* w2_t   = (__hip_bfloat16*)take((size_t)Dm * FFd * 2);
  __hip_bfloat16* xn     = (__hip_bfloat16*)take((size_t)Mrows * Dm * 2);  // reused as LN2 out
  __hip_bfloat16* qb     = (__hip_bfloat16*)take((size_t)Mrows * Dm * 2);
  __hip_bfloat16* kb     = (__hip_bfloat16*)take((size_t)Mrows * Dm * 2);
  __hip_bfloat16* vtb    = (__hip_bfloat16*)take((size_t)Mrows * Dm * 2);
  __hip_bfloat16* attn   = (__hip_bfloat16*)take((size_t)Mrows * Dm * 2);
  float*          x1     = (float*)take((size_t)Mrows * Dm * 4);
  __hip_bfloat16* gbuf   = (__hip_bfloat16*)take((size_t)Mrows * FFd * 2);

  const dim3 blk(256);
  // weight transposes (f32 [K][N] -> bf16 [N][K])
  transpose_cast_k<<<dim3(3 * Dm / 32, Dm / 32), blk, 0, stream>>>(qkv_w, wqkv_t, Dm, 3 * Dm);
  transpose_cast_k<<<dim3(Dm / 32, Dm / 32), blk, 0, stream>>>(out_w, wout_t, Dm, Dm);
  transpose_cast_k<<<dim3(FFd / 32, Dm / 32), blk, 0, stream>>>(w1, w1_t, Dm, FFd);
  transpose_cast_k<<<dim3(Dm / 32, FFd / 32), blk, 0, stream>>>(w2, w2_t, FFd, Dm);
  // LN1
  ln_kernel<<<dim3(Mrows), blk, 0, stream>>>(x, ln1_g, ln1_b, xn);
  // QKV projection, scatter q/k/v^T
  gemm_bt<0><<<dim3(3 * Dm / 128, Mrows / 128), blk, 0, stream>>>(
      xn, wqkv_t, qkv_b, nullptr, nullptr, nullptr, qb, kb, vtb, 3 * Dm, Dm);
  // attention (swapped 32x32 MFMA): 64 bh x 8 q-tiles of 128 rows
  attn_kernel<<<dim3(Bq * Hh * (Nseq / 128)), blk, 0, stream>>>(qb, kb, vtb, attn);
  // output projection + residual -> x1 (f32)
  gemm_bt<1><<<dim3(Dm / 128, Mrows / 128), blk, 0, stream>>>(
      attn, wout_t, out_b, x, x1, nullptr, nullptr, nullptr, nullptr, Dm, Dm);
  // LN2
  ln_kernel<<<dim3(Mrows), blk, 0, stream>>>(x1, ln2_g, ln2_b, xn);
  // FFN1 + GELU -> gbuf (bf16)
  gemm_bt<2><<<dim3(FFd / 128, Mrows / 128), blk, 0, stream>>>(
      xn, w1_t, b1, nullptr, nullptr, gbuf, nullptr, nullptr, nullptr, FFd, Dm);
  // FFN2 + residual -> out (f32)
  gemm_bt<1><<<dim3(Dm / 128, Mrows / 128), blk, 0, stream>>>(
      gbuf, w2_t, b2, x1, outp, nullptr, nullptr, nullptr, nullptr, Dm, FFd);
}